// Round 16
// baseline (127.346 us; speedup 1.0000x reference)
//
#include <hip/hip_runtime.h>
#include <hip/hip_bf16.h>
#include <cstdint>

typedef __attribute__((ext_vector_type(8))) short bf16x8;
typedef __attribute__((ext_vector_type(4))) float f32x4;

#define PLDT 72   // attn P^T LDS row stride

static __device__ __forceinline__ unsigned short f2bf(float x) {
    __hip_bfloat16 h = __float2bfloat16(x);
    union { __hip_bfloat16 b; unsigned short u; } c; c.b = h; return c.u;
}
static __device__ __forceinline__ float bf2f(unsigned short b) {
    union { float f; uint32_t u; } v; v.u = ((uint32_t)b) << 16;
    return v.f;
}
static __device__ __forceinline__ float exp2b(float x) {
    return __builtin_amdgcn_exp2f(x);
}
static __device__ __forceinline__ unsigned int cvt_pk_bf16(float lo, float hi) {
    unsigned int r;
    asm("v_cvt_pk_bf16_f32 %0, %1, %2" : "=v"(r) : "v"(lo), "v"(hi));
    return r;
}
static __device__ __forceinline__ void gload_lds16(const unsigned short* g, unsigned short* l) {
    __builtin_amdgcn_global_load_lds(
        (const __attribute__((address_space(1))) void*)g,
        (__attribute__((address_space(3))) void*)l, 16, 0, 0);
}

// ---------------------------------------------------------------------------
// fp32 -> bf16 convert pass (unchanged).
// ---------------------------------------------------------------------------
__global__ __launch_bounds__(256) void cvt_all(
    const float* __restrict__ xq, const float* __restrict__ xk, const float* __restrict__ xv,
    const float* __restrict__ wq, const float* __restrict__ wk, const float* __restrict__ wv,
    unsigned short* __restrict__ oxq, unsigned short* __restrict__ oxk, unsigned short* __restrict__ oxv,
    unsigned short* __restrict__ owq, unsigned short* __restrict__ owk, unsigned short* __restrict__ owv) {
    const int z = blockIdx.z;
    const float* in = (z == 0) ? xq : (z == 1) ? xk : (z == 2) ? xv
                      : (z == 3) ? wq : (z == 4) ? wk : wv;
    unsigned short* out = (z == 0) ? oxq : (z == 1) ? oxk : (z == 2) ? oxv
                          : (z == 3) ? owq : (z == 4) ? owk : owv;
    const int n8 = (z < 3) ? 524288 : 131072;
    int i = blockIdx.x * 256 + threadIdx.x;
    if (i >= n8) return;
    const float4* ip = (const float4*)in;
    float4 a = ip[2 * i];
    float4 b = ip[2 * i + 1];
    uint4 r;
    r.x = cvt_pk_bf16(a.x, a.y);
    r.y = cvt_pk_bf16(a.z, a.w);
    r.z = cvt_pk_bf16(b.x, b.y);
    r.w = cvt_pk_bf16(b.z, b.w);
    *(uint4*)(out + (size_t)i * 8) = r;
}

// ---------------------------------------------------------------------------
// Projection GEMM, m97 structure (unchanged from round 13). z=0: Q row-major;
// z=1: K and z=2: V^T in MFMA-fragment order.
// ---------------------------------------------------------------------------
__global__ __launch_bounds__(256) void proj_gemm_bf16(
    const unsigned short* __restrict__ Xqb, const unsigned short* __restrict__ Xkb,
    const unsigned short* __restrict__ Xvb,
    const unsigned short* __restrict__ Wqb, const unsigned short* __restrict__ Wkb,
    const unsigned short* __restrict__ Wvb,
    const float* __restrict__ bqp, const float* __restrict__ bkp, const float* __restrict__ bvp,
    unsigned short* __restrict__ dq, unsigned short* __restrict__ dk, unsigned short* __restrict__ dv) {
    __shared__ unsigned short a_lds[128 * 64];
    __shared__ unsigned short b_lds[128 * 64];

    const int z = blockIdx.z;
    const unsigned short* X = (z == 0) ? Xqb : (z == 1) ? Xkb : Xvb;
    const unsigned short* W = (z == 0) ? Wqb : (z == 1) ? Wkb : Wvb;
    const float* bias = (z == 0) ? bqp : (z == 1) ? bkp : bvp;
    unsigned short* dst = (z == 0) ? dq : (z == 1) ? dk : dv;

    const int tid = threadIdx.x;
    const int lane = tid & 63;
    const int w = tid >> 6;
    const int lr = lane & 15;
    const int lg = lane >> 4;
    const int m0 = blockIdx.x * 128;
    const int e0 = blockIdx.y * 128;
    const int wrow = (w >> 1) * 64;
    const int wcol = (w & 1) * 64;

    f32x4 acc[4][4] = {};

#pragma unroll 1
    for (int t = 0; t < 16; ++t) {
        const int k0 = t * 64;
        __syncthreads();
#pragma unroll
        for (int i = 0; i < 4; ++i) {
            int c = i * 256 + w * 64 + lane;
            int row = c >> 3;
            int col = (c & 7) * 8;
            gload_lds16(X + (size_t)(m0 + row) * 1024 + k0 + col,
                        a_lds + (size_t)(i * 256 + w * 64) * 8);
            gload_lds16(W + (size_t)(e0 + row) * 1024 + k0 + col,
                        b_lds + (size_t)(i * 256 + w * 64) * 8);
        }
        __syncthreads();

#pragma unroll
        for (int ks = 0; ks < 2; ++ks) {
            const int kk = ks * 32 + lg * 8;
            bf16x8 af[4], bfr[4];
#pragma unroll
            for (int mt = 0; mt < 4; ++mt)
                af[mt] = *(const bf16x8*)(a_lds + (wrow + mt * 16 + lr) * 64 + kk);
#pragma unroll
            for (int nt = 0; nt < 4; ++nt)
                bfr[nt] = *(const bf16x8*)(b_lds + (wcol + nt * 16 + lr) * 64 + kk);
            __builtin_amdgcn_s_setprio(1);
#pragma unroll
            for (int mt = 0; mt < 4; ++mt)
#pragma unroll
                for (int nt = 0; nt < 4; ++nt)
                    acc[mt][nt] = __builtin_amdgcn_mfma_f32_16x16x32_bf16(
                        af[mt], bfr[nt], acc[mt][nt], 0, 0, 0);
            __builtin_amdgcn_s_setprio(0);
        }
    }

    for (int mt = 0; mt < 4; ++mt)
        for (int nt = 0; nt < 4; ++nt)
            for (int i = 0; i < 4; ++i) {
                int m = m0 + wrow + mt * 16 + lg * 4 + i;
                int e = e0 + wcol + nt * 16 + lr;
                float val = acc[mt][nt][i] + bias[e];
                int b = m >> 11, s = m & 2047;
                int h = e >> 6, d = e & 63;
                size_t headoff = (((size_t)b * 16 + h) * 131072);
                if (z == 0) {
                    dst[headoff + (size_t)s * 64 + d] = f2bf(val);
                } else if (z == 1) {
                    int tt = s >> 6, kvr = s & 63;
                    int fmt = kvr >> 4, flr = kvr & 15;
                    int ks = d >> 5, lg3 = (d >> 3) & 3, j = d & 7;
                    dst[headoff + tt * 4096 + (ks * 4 + fmt) * 512 + (lg3 * 16 + flr) * 8 + j] = f2bf(val);
                } else {
                    int tt = s >> 6, kvc = s & 63;
                    int fmt = d >> 4, flr = d & 15;
                    int ks = kvc >> 5, lg3 = (kvc >> 3) & 3, j = kvc & 7;
                    dst[headoff + tt * 4096 + (ks * 4 + fmt) * 512 + (lg3 * 16 + flr) * 8 + j] = f2bf(val);
                }
            }
}

// ---------------------------------------------------------------------------
// Flash attention v14 = round-13 base (PASSING: barrier-free, fragment-order
// K/V from L2, no-max softmax, VALU+shfl lsum) restructured as a TWO-CHAIN
// interleave: the no-max softmax makes KV tiles fully independent, so each
// loop body processes tiles t and t+16 as two independent copies of the
// proven r13 chain (separate P buffers pw0/pw1; both accumulate the same
// o/lsum — pure sums, order-free). Chain B's loads overlap chain A's compute
// and vice versa, filling the exposed-latency stalls r13's counters showed.
// lsum stays on the proven VALU + per-iter shfl_xor path (the ones-MFMA
// variant failed twice and is abandoned).
// ---------------------------------------------------------------------------
__global__ __launch_bounds__(256) void attn_kernel(
    const unsigned short* __restrict__ Qh,
    const unsigned short* __restrict__ Kf,
    const unsigned short* __restrict__ Vf,
    const unsigned char* __restrict__ mask,
    float* __restrict__ Out) {
    __shared__ unsigned short pbuf[4][2][32 * PLDT];  // [wave][chain][q][kv]

    const int tid = threadIdx.x;
    const int lane = tid & 63;
    const int w = tid >> 6;
    const int lr = lane & 15;
    const int lg = lane >> 4;

    // T1 XCD swizzle: 512 workgroups, 64 per XCD
    const int bid = blockIdx.x;
    const int wk = (bid & 7) * 64 + (bid >> 3);
    const int x = wk & 15;
    const int bh = wk >> 4;
    const int h = bh & 15;
    const int b = bh >> 4;
    const int q0 = x * 128;

    const size_t headoff = (((size_t)b * 16) + h) * 131072;
    const unsigned short* Qp = Qh + headoff;
    const unsigned char* maskp = mask + b * 2048;
    unsigned short* pw0 = pbuf[w][0];
    unsigned short* pw1 = pbuf[w][1];

    // fragment-order bases: + t*4096 + (ks*4+mt)*512 per tile/fragment
    const unsigned short* kfb = Kf + headoff + (size_t)lane * 8;
    const unsigned short* vfb = Vf + headoff + (size_t)lane * 8;

    // Q as B-operand (col=q=lr, k=lg*8+j), scaled by 1/sqrt(64)*log2(e)
    const float qscale = 0.125f * 1.44269504088896340736f;
    bf16x8 qf[2][2];
#pragma unroll
    for (int qh = 0; qh < 2; ++qh) {
        int row = q0 + w * 32 + qh * 16 + lr;
#pragma unroll
        for (int ks = 0; ks < 2; ++ks) {
            bf16x8 t = *(const bf16x8*)(Qp + (size_t)row * 64 + ks * 32 + lg * 8);
#pragma unroll
            for (int j = 0; j < 8; ++j)
                t[j] = (short)f2bf(bf2f((unsigned short)t[j]) * qscale);
            qf[qh][ks] = t;
        }
    }

    f32x4 o[2][4] = {};           // O^T: lane holds q=lr, d = mt*16+lg*4+i
    float lsum[2] = {0.f, 0.f};   // per-q-half denominator (both chains)

#pragma unroll 1
    for (int t = 0; t < 16; ++t) {
        const unsigned short* ktA = kfb + t * 4096;
        const unsigned short* ktB = kfb + (t + 16) * 4096;
        const unsigned short* vtA = vfb + t * 4096;
        const unsigned short* vtB = vfb + (t + 16) * 4096;

        // K fragments, both chains (16 coalesced 1KB loads in flight)
        bf16x8 kfA[2][4], kfB[2][4];
#pragma unroll
        for (int ks = 0; ks < 2; ++ks)
#pragma unroll
            for (int mt = 0; mt < 4; ++mt) {
                kfA[ks][mt] = *(const bf16x8*)(ktA + (ks * 4 + mt) * 512);
                kfB[ks][mt] = *(const bf16x8*)(ktB + (ks * 4 + mt) * 512);
            }

        // S^T = K . Q^T, both chains interleaved
        f32x4 sA[2][4] = {}, sB[2][4] = {};
        __builtin_amdgcn_s_setprio(1);
#pragma unroll
        for (int ks = 0; ks < 2; ++ks)
#pragma unroll
            for (int mt = 0; mt < 4; ++mt) {
                sA[0][mt] = __builtin_amdgcn_mfma_f32_16x16x32_bf16(kfA[ks][mt], qf[0][ks], sA[0][mt], 0, 0, 0);
                sA[1][mt] = __builtin_amdgcn_mfma_f32_16x16x32_bf16(kfA[ks][mt], qf[1][ks], sA[1][mt], 0, 0, 0);
                sB[0][mt] = __builtin_amdgcn_mfma_f32_16x16x32_bf16(kfB[ks][mt], qf[0][ks], sB[0][mt], 0, 0, 0);
                sB[1][mt] = __builtin_amdgcn_mfma_f32_16x16x32_bf16(kfB[ks][mt], qf[1][ks], sB[1][mt], 0, 0, 0);
            }
        __builtin_amdgcn_s_setprio(0);

        // V fragments, both chains: issue now; consumed after softmax
        bf16x8 vfA[2][4], vfB[2][4];
#pragma unroll
        for (int ks = 0; ks < 2; ++ks)
#pragma unroll
            for (int mt = 0; mt < 4; ++mt) {
                vfA[ks][mt] = *(const bf16x8*)(vtA + (ks * 4 + mt) * 512);
                vfB[ks][mt] = *(const bf16x8*)(vtB + (ks * 4 + mt) * 512);
            }

        unsigned long long mbitsA = __ballot(maskp[t * 64 + lane] != 0);
        unsigned long long mbitsB = __ballot(maskp[(t + 16) * 64 + lane] != 0);
        if (mbitsA) {
#pragma unroll
            for (int qh = 0; qh < 2; ++qh)
#pragma unroll
                for (int mt = 0; mt < 4; ++mt)
#pragma unroll
                    for (int i = 0; i < 4; ++i)
                        if ((mbitsA >> (mt * 16 + lg * 4 + i)) & 1ull) sA[qh][mt][i] = -1e30f;
        }
        if (mbitsB) {
#pragma unroll
            for (int qh = 0; qh < 2; ++qh)
#pragma unroll
                for (int mt = 0; mt < 4; ++mt)
#pragma unroll
                    for (int i = 0; i < 4; ++i)
                        if ((mbitsB >> (mt * 16 + lg * 4 + i)) & 1ull) sB[qh][mt][i] = -1e30f;
        }

        // softmax + pack, chain A -> pw0  (proven r13 path: VALU lsum + shfl)
#pragma unroll
        for (int qh = 0; qh < 2; ++qh) {
            float p[4][4];
            float ls = 0.f;
#pragma unroll
            for (int mt = 0; mt < 4; ++mt)
#pragma unroll
                for (int i = 0; i < 4; ++i) {
                    p[mt][i] = exp2b(sA[qh][mt][i]);
                    ls += p[mt][i];
                }
            ls += __shfl_xor(ls, 16);
            ls += __shfl_xor(ls, 32);
            lsum[qh] += ls;
#pragma unroll
            for (int mt = 0; mt < 4; ++mt) {
                uint2 pr;
                pr.x = cvt_pk_bf16(p[mt][0], p[mt][1]);
                pr.y = cvt_pk_bf16(p[mt][2], p[mt][3]);
                *(uint2*)(&pw0[(qh * 16 + lr) * PLDT + mt * 16 + lg * 4]) = pr;
            }
        }
        // softmax + pack, chain B -> pw1
#pragma unroll
        for (int qh = 0; qh < 2; ++qh) {
            float p[4][4];
            float ls = 0.f;
#pragma unroll
            for (int mt = 0; mt < 4; ++mt)
#pragma unroll
                for (int i = 0; i < 4; ++i) {
                    p[mt][i] = exp2b(sB[qh][mt][i]);
                    ls += p[mt][i];
                }
            ls += __shfl_xor(ls, 16);
            ls += __shfl_xor(ls, 32);
            lsum[qh] += ls;
#pragma unroll
            for (int mt = 0; mt < 4; ++mt) {
                uint2 pr;
                pr.x = cvt_pk_bf16(p[mt][0], p[mt][1]);
                pr.y = cvt_pk_bf16(p[mt][2], p[mt][3]);
                *(uint2*)(&pw1[(qh * 16 + lr) * PLDT + mt * 16 + lg * 4]) = pr;
            }
        }

        // PV both chains: O^T += V^T . P^T
        __builtin_amdgcn_s_setprio(1);
#pragma unroll
        for (int qh = 0; qh < 2; ++qh)
#pragma unroll
            for (int ks = 0; ks < 2; ++ks) {
                bf16x8 pfrA = *(const bf16x8*)(&pw0[(qh * 16 + lr) * PLDT + ks * 32 + lg * 8]);
#pragma unroll
                for (int mt = 0; mt < 4; ++mt)
                    o[qh][mt] = __builtin_amdgcn_mfma_f32_16x16x32_bf16(vfA[ks][mt], pfrA, o[qh][mt], 0, 0, 0);
                bf16x8 pfrB = *(const bf16x8*)(&pw1[(qh * 16 + lr) * PLDT + ks * 32 + lg * 8]);
#pragma unroll
                for (int mt = 0; mt < 4; ++mt)
                    o[qh][mt] = __builtin_amdgcn_mfma_f32_16x16x32_bf16(vfB[ks][mt], pfrB, o[qh][mt], 0, 0, 0);
            }
        __builtin_amdgcn_s_setprio(0);
    }

    // epilogue (wave-private): transpose O^T -> [q][d] then coalesced stores
    float* ep = (float*)pw0;
#pragma unroll
    for (int qh = 0; qh < 2; ++qh) {
        float rinv = 1.0f / lsum[qh];
#pragma unroll
        for (int mt = 0; mt < 4; ++mt)
#pragma unroll
            for (int i = 0; i < 4; ++i)
                ep[lr * 68 + mt * 16 + lg * 4 + i] = o[qh][mt][i] * rinv;
#pragma unroll
        for (int j = 0; j < 4; ++j) {
            int id = lane + 64 * j;
            int row = id >> 4;
            int c4 = (id & 15) << 2;
            float4 val = *(const float4*)(&ep[row * 68 + c4]);
            *(float4*)(&Out[((size_t)b * 2048 + q0 + w * 32 + qh * 16 + row) * 1024 + h * 64 + c4]) = val;
        }
    }
}

extern "C" void kernel_launch(void* const* d_in, const int* in_sizes, int n_in,
                              void* d_out, int out_size, void* d_ws, size_t ws_size,
                              hipStream_t stream) {
    const float* v = (const float*)d_in[0];
    const float* k = (const float*)d_in[1];
    const float* q = (const float*)d_in[2];
    const unsigned char* mask = (const unsigned char*)d_in[3];
    const float* Wq = (const float*)d_in[4];
    const float* bq = (const float*)d_in[5];
    const float* Wk = (const float*)d_in[6];
    const float* bk = (const float*)d_in[7];
    const float* Wv = (const float*)d_in[8];
    const float* bv = (const float*)d_in[9];
    float* out = (float*)d_out;

    unsigned short* ws = (unsigned short*)d_ws;
    unsigned short* qh  = ws;                 // 4096*1024 each
    unsigned short* kh  = ws + 4194304;       // K in fragment order
    unsigned short* vT  = ws + 8388608;       // V^T in fragment order
    unsigned short* xqb = ws + 12582912;      // bf16 X inputs
    unsigned short* xkb = ws + 16777216;
    unsigned short* xvb = ws + 20971520;
    unsigned short* wqb = ws + 25165824;      // bf16 W inputs
    unsigned short* wkb = ws + 26214400;
    unsigned short* wvb = ws + 27262976;

    cvt_all<<<dim3(2048, 1, 6), 256, 0, stream>>>(q, k, v, Wq, Wk, Wv,
                                                  xqb, xkb, xvb, wqb, wkb, wvb);

    dim3 pgrid(32, 8, 3);
    proj_gemm_bf16<<<pgrid, 256, 0, stream>>>(xqb, xkb, xvb, wqb, wkb, wvb,
                                              bq, bk, bv, qh, kh, vT);

    attn_kernel<<<dim3(512), 256, 0, stream>>>(qh, kh, vT, mask, out);
}

// Round 17
// 124.383 us; speedup vs baseline: 1.0238x; 1.0238x over previous
//
#include <hip/hip_runtime.h>
#include <hip/hip_bf16.h>
#include <cstdint>

typedef __attribute__((ext_vector_type(8))) short bf16x8;
typedef __attribute__((ext_vector_type(4))) float f32x4;

#define PLDT 72   // attn P^T LDS row stride

static __device__ __forceinline__ unsigned short f2bf(float x) {
    __hip_bfloat16 h = __float2bfloat16(x);
    union { __hip_bfloat16 b; unsigned short u; } c; c.b = h; return c.u;
}
static __device__ __forceinline__ float bf2f(unsigned short b) {
    union { float f; uint32_t u; } v; v.u = ((uint32_t)b) << 16;
    return v.f;
}
static __device__ __forceinline__ float exp2b(float x) {
    return __builtin_amdgcn_exp2f(x);
}
static __device__ __forceinline__ unsigned int cvt_pk_bf16(float lo, float hi) {
    unsigned int r;
    asm("v_cvt_pk_bf16_f32 %0, %1, %2" : "=v"(r) : "v"(lo), "v"(hi));
    return r;
}
static __device__ __forceinline__ void gload_lds16(const unsigned short* g, unsigned short* l) {
    __builtin_amdgcn_global_load_lds(
        (const __attribute__((address_space(1))) void*)g,
        (__attribute__((address_space(3))) void*)l, 16, 0, 0);
}

// ---------------------------------------------------------------------------
// fp32 -> bf16 convert pass (unchanged).
// ---------------------------------------------------------------------------
__global__ __launch_bounds__(256) void cvt_all(
    const float* __restrict__ xq, const float* __restrict__ xk, const float* __restrict__ xv,
    const float* __restrict__ wq, const float* __restrict__ wk, const float* __restrict__ wv,
    unsigned short* __restrict__ oxq, unsigned short* __restrict__ oxk, unsigned short* __restrict__ oxv,
    unsigned short* __restrict__ owq, unsigned short* __restrict__ owk, unsigned short* __restrict__ owv) {
    const int z = blockIdx.z;
    const float* in = (z == 0) ? xq : (z == 1) ? xk : (z == 2) ? xv
                      : (z == 3) ? wq : (z == 4) ? wk : wv;
    unsigned short* out = (z == 0) ? oxq : (z == 1) ? oxk : (z == 2) ? oxv
                          : (z == 3) ? owq : (z == 4) ? owk : owv;
    const int n8 = (z < 3) ? 524288 : 131072;
    int i = blockIdx.x * 256 + threadIdx.x;
    if (i >= n8) return;
    const float4* ip = (const float4*)in;
    float4 a = ip[2 * i];
    float4 b = ip[2 * i + 1];
    uint4 r;
    r.x = cvt_pk_bf16(a.x, a.y);
    r.y = cvt_pk_bf16(a.z, a.w);
    r.z = cvt_pk_bf16(b.x, b.y);
    r.w = cvt_pk_bf16(b.z, b.w);
    *(uint4*)(out + (size_t)i * 8) = r;
}

// ---------------------------------------------------------------------------
// Projection GEMM, m97 structure (unchanged from round 13). z=0: Q row-major;
// z=1: K and z=2: V^T in MFMA-fragment order.
// ---------------------------------------------------------------------------
__global__ __launch_bounds__(256) void proj_gemm_bf16(
    const unsigned short* __restrict__ Xqb, const unsigned short* __restrict__ Xkb,
    const unsigned short* __restrict__ Xvb,
    const unsigned short* __restrict__ Wqb, const unsigned short* __restrict__ Wkb,
    const unsigned short* __restrict__ Wvb,
    const float* __restrict__ bqp, const float* __restrict__ bkp, const float* __restrict__ bvp,
    unsigned short* __restrict__ dq, unsigned short* __restrict__ dk, unsigned short* __restrict__ dv) {
    __shared__ unsigned short a_lds[128 * 64];
    __shared__ unsigned short b_lds[128 * 64];

    const int z = blockIdx.z;
    const unsigned short* X = (z == 0) ? Xqb : (z == 1) ? Xkb : Xvb;
    const unsigned short* W = (z == 0) ? Wqb : (z == 1) ? Wkb : Wvb;
    const float* bias = (z == 0) ? bqp : (z == 1) ? bkp : bvp;
    unsigned short* dst = (z == 0) ? dq : (z == 1) ? dk : dv;

    const int tid = threadIdx.x;
    const int lane = tid & 63;
    const int w = tid >> 6;
    const int lr = lane & 15;
    const int lg = lane >> 4;
    const int m0 = blockIdx.x * 128;
    const int e0 = blockIdx.y * 128;
    const int wrow = (w >> 1) * 64;
    const int wcol = (w & 1) * 64;

    f32x4 acc[4][4] = {};

#pragma unroll 1
    for (int t = 0; t < 16; ++t) {
        const int k0 = t * 64;
        __syncthreads();
#pragma unroll
        for (int i = 0; i < 4; ++i) {
            int c = i * 256 + w * 64 + lane;
            int row = c >> 3;
            int col = (c & 7) * 8;
            gload_lds16(X + (size_t)(m0 + row) * 1024 + k0 + col,
                        a_lds + (size_t)(i * 256 + w * 64) * 8);
            gload_lds16(W + (size_t)(e0 + row) * 1024 + k0 + col,
                        b_lds + (size_t)(i * 256 + w * 64) * 8);
        }
        __syncthreads();

#pragma unroll
        for (int ks = 0; ks < 2; ++ks) {
            const int kk = ks * 32 + lg * 8;
            bf16x8 af[4], bfr[4];
#pragma unroll
            for (int mt = 0; mt < 4; ++mt)
                af[mt] = *(const bf16x8*)(a_lds + (wrow + mt * 16 + lr) * 64 + kk);
#pragma unroll
            for (int nt = 0; nt < 4; ++nt)
                bfr[nt] = *(const bf16x8*)(b_lds + (wcol + nt * 16 + lr) * 64 + kk);
            __builtin_amdgcn_s_setprio(1);
#pragma unroll
            for (int mt = 0; mt < 4; ++mt)
#pragma unroll
                for (int nt = 0; nt < 4; ++nt)
                    acc[mt][nt] = __builtin_amdgcn_mfma_f32_16x16x32_bf16(
                        af[mt], bfr[nt], acc[mt][nt], 0, 0, 0);
            __builtin_amdgcn_s_setprio(0);
        }
    }

    for (int mt = 0; mt < 4; ++mt)
        for (int nt = 0; nt < 4; ++nt)
            for (int i = 0; i < 4; ++i) {
                int m = m0 + wrow + mt * 16 + lg * 4 + i;
                int e = e0 + wcol + nt * 16 + lr;
                float val = acc[mt][nt][i] + bias[e];
                int b = m >> 11, s = m & 2047;
                int h = e >> 6, d = e & 63;
                size_t headoff = (((size_t)b * 16 + h) * 131072);
                if (z == 0) {
                    dst[headoff + (size_t)s * 64 + d] = f2bf(val);
                } else if (z == 1) {
                    int tt = s >> 6, kvr = s & 63;
                    int fmt = kvr >> 4, flr = kvr & 15;
                    int ks = d >> 5, lg3 = (d >> 3) & 3, j = d & 7;
                    dst[headoff + tt * 4096 + (ks * 4 + fmt) * 512 + (lg3 * 16 + flr) * 8 + j] = f2bf(val);
                } else {
                    int tt = s >> 6, kvc = s & 63;
                    int fmt = d >> 4, flr = d & 15;
                    int ks = kvc >> 5, lg3 = (kvc >> 3) & 3, j = kvc & 7;
                    dst[headoff + tt * 4096 + (ks * 4 + fmt) * 512 + (lg3 * 16 + flr) * 8 + j] = f2bf(val);
                }
            }
}

// ---------------------------------------------------------------------------
// Flash attention v15 = round-13 kernel (PASSING base: barrier-free,
// fragment-order K/V from L2, no-max softmax, VALU+shfl lsum) with EXACTLY
// ONE change: K register double-buffer. K(t+1)'s 8 fragment loads issue right
// after QK^T(t) consumes kf — their ~300cyc L2 latency hides under the
// softmax + PV of tile t instead of being exposed at the top of iter t+1.
// (This was the untested half of round 14; round 15 proved the ones-MFMA was
// that round's sole bug. lsum stays on the proven VALU+shfl path.)
// ---------------------------------------------------------------------------
__device__ __forceinline__ void load_kf(bf16x8 (&kf)[2][4], const unsigned short* kt) {
#pragma unroll
    for (int ks = 0; ks < 2; ++ks)
#pragma unroll
        for (int mt = 0; mt < 4; ++mt)
            kf[ks][mt] = *(const bf16x8*)(kt + (ks * 4 + mt) * 512);
}

__device__ __forceinline__ void attn_step(
    const bf16x8 (&kf)[2][4],          // K fragments for tile t (ready)
    bf16x8 (&kfn)[2][4],               // prefetch target for tile t+1
    const unsigned short* ktn,         // K tile t+1 base
    const unsigned short* vt,          // V tile t base
    const bf16x8 (&qf)[2][2],
    const unsigned char* maskp, int kv0,
    f32x4 (&o)[2][4], float (&lsum)[2],
    unsigned short* pw, int lr, int lg, int lane) {
    // S^T[kv][q] = K . Q^T
    f32x4 s[2][4] = {};
    __builtin_amdgcn_s_setprio(1);
#pragma unroll
    for (int ks = 0; ks < 2; ++ks)
#pragma unroll
        for (int mt = 0; mt < 4; ++mt) {
            s[0][mt] = __builtin_amdgcn_mfma_f32_16x16x32_bf16(kf[ks][mt], qf[0][ks], s[0][mt], 0, 0, 0);
            s[1][mt] = __builtin_amdgcn_mfma_f32_16x16x32_bf16(kf[ks][mt], qf[1][ks], s[1][mt], 0, 0, 0);
        }
    __builtin_amdgcn_s_setprio(0);

    // prefetch K(t+1): kf regs are dead; latency hides under softmax + PV
    load_kf(kfn, ktn);

    // V fragments for tile t: consumed after softmax
    bf16x8 vf[2][4];
#pragma unroll
    for (int ks = 0; ks < 2; ++ks)
#pragma unroll
        for (int mt = 0; mt < 4; ++mt)
            vf[ks][mt] = *(const bf16x8*)(vt + (ks * 4 + mt) * 512);

    unsigned long long mbits = __ballot(maskp[kv0 + lane] != 0);
    if (mbits) {
#pragma unroll
        for (int qh = 0; qh < 2; ++qh)
#pragma unroll
            for (int mt = 0; mt < 4; ++mt)
#pragma unroll
                for (int i = 0; i < 4; ++i)
                    if ((mbits >> (mt * 16 + lg * 4 + i)) & 1ull) s[qh][mt][i] = -1e30f;
    }

    // no-max softmax (r13-proven): p = exp2(s), VALU lsum + 2 shfl, pack->LDS
#pragma unroll
    for (int qh = 0; qh < 2; ++qh) {
        float p[4][4];
        float ls = 0.f;
#pragma unroll
        for (int mt = 0; mt < 4; ++mt)
#pragma unroll
            for (int i = 0; i < 4; ++i) {
                p[mt][i] = exp2b(s[qh][mt][i]);
                ls += p[mt][i];
            }
        ls += __shfl_xor(ls, 16);
        ls += __shfl_xor(ls, 32);
        lsum[qh] += ls;
#pragma unroll
        for (int mt = 0; mt < 4; ++mt) {
            uint2 pr;
            pr.x = cvt_pk_bf16(p[mt][0], p[mt][1]);
            pr.y = cvt_pk_bf16(p[mt][2], p[mt][3]);
            *(uint2*)(&pw[(qh * 16 + lr) * PLDT + mt * 16 + lg * 4]) = pr;
        }
    }

    // O^T += V^T . P^T
    __builtin_amdgcn_s_setprio(1);
#pragma unroll
    for (int qh = 0; qh < 2; ++qh)
#pragma unroll
        for (int ks = 0; ks < 2; ++ks) {
            bf16x8 pfr = *(const bf16x8*)(&pw[(qh * 16 + lr) * PLDT + ks * 32 + lg * 8]);
#pragma unroll
            for (int mt = 0; mt < 4; ++mt)
                o[qh][mt] = __builtin_amdgcn_mfma_f32_16x16x32_bf16(vf[ks][mt], pfr, o[qh][mt], 0, 0, 0);
        }
    __builtin_amdgcn_s_setprio(0);
}

__global__ __launch_bounds__(256) void attn_kernel(
    const unsigned short* __restrict__ Qh,
    const unsigned short* __restrict__ Kf,
    const unsigned short* __restrict__ Vf,
    const unsigned char* __restrict__ mask,
    float* __restrict__ Out) {
    __shared__ unsigned short pbuf[4][32 * PLDT];  // per-wave P [32 q][64 kv]

    const int tid = threadIdx.x;
    const int lane = tid & 63;
    const int w = tid >> 6;
    const int lr = lane & 15;
    const int lg = lane >> 4;

    // T1 XCD swizzle: 512 workgroups, 64 per XCD
    const int bid = blockIdx.x;
    const int wk = (bid & 7) * 64 + (bid >> 3);
    const int x = wk & 15;
    const int bh = wk >> 4;
    const int h = bh & 15;
    const int b = bh >> 4;
    const int q0 = x * 128;

    const size_t headoff = (((size_t)b * 16) + h) * 131072;
    const unsigned short* Qp = Qh + headoff;
    const unsigned char* maskp = mask + b * 2048;
    unsigned short* pw = pbuf[w];

    const unsigned short* kfb = Kf + headoff + (size_t)lane * 8;
    const unsigned short* vfb = Vf + headoff + (size_t)lane * 8;

    // Q as B-operand (col=q=lr, k=lg*8+j), scaled by 1/sqrt(64)*log2(e)
    const float qscale = 0.125f * 1.44269504088896340736f;
    bf16x8 qf[2][2];
#pragma unroll
    for (int qh = 0; qh < 2; ++qh) {
        int row = q0 + w * 32 + qh * 16 + lr;
#pragma unroll
        for (int ks = 0; ks < 2; ++ks) {
            bf16x8 t = *(const bf16x8*)(Qp + (size_t)row * 64 + ks * 32 + lg * 8);
#pragma unroll
            for (int j = 0; j < 8; ++j)
                t[j] = (short)f2bf(bf2f((unsigned short)t[j]) * qscale);
            qf[qh][ks] = t;
        }
    }

    f32x4 o[2][4] = {};           // O^T: lane holds q=lr, d = mt*16+lg*4+i
    float lsum[2] = {0.f, 0.f};

    // K double-buffer prologue
    bf16x8 kfA[2][4], kfB[2][4];
    load_kf(kfA, kfb);

#pragma unroll 1
    for (int t = 0; t < 32; t += 2) {
        attn_step(kfA, kfB, kfb + (t + 1) * 4096, vfb + t * 4096,
                  qf, maskp, t * 64, o, lsum, pw, lr, lg, lane);
        int tn = (t + 2 < 32) ? (t + 2) : 31;  // clamped tail prefetch
        attn_step(kfB, kfA, kfb + tn * 4096, vfb + (t + 1) * 4096,
                  qf, maskp, (t + 1) * 64, o, lsum, pw, lr, lg, lane);
    }

    // epilogue (wave-private): transpose O^T -> [q][d] then coalesced stores
    float* ep = (float*)pw;
#pragma unroll
    for (int qh = 0; qh < 2; ++qh) {
        float rinv = 1.0f / lsum[qh];
#pragma unroll
        for (int mt = 0; mt < 4; ++mt)
#pragma unroll
            for (int i = 0; i < 4; ++i)
                ep[lr * 68 + mt * 16 + lg * 4 + i] = o[qh][mt][i] * rinv;
#pragma unroll
        for (int j = 0; j < 4; ++j) {
            int id = lane + 64 * j;
            int row = id >> 4;
            int c4 = (id & 15) << 2;
            float4 val = *(const float4*)(&ep[row * 68 + c4]);
            *(float4*)(&Out[((size_t)b * 2048 + q0 + w * 32 + qh * 16 + row) * 1024 + h * 64 + c4]) = val;
        }
    }
}

extern "C" void kernel_launch(void* const* d_in, const int* in_sizes, int n_in,
                              void* d_out, int out_size, void* d_ws, size_t ws_size,
                              hipStream_t stream) {
    const float* v = (const float*)d_in[0];
    const float* k = (const float*)d_in[1];
    const float* q = (const float*)d_in[2];
    const unsigned char* mask = (const unsigned char*)d_in[3];
    const float* Wq = (const float*)d_in[4];
    const float* bq = (const float*)d_in[5];
    const float* Wk = (const float*)d_in[6];
    const float* bk = (const float*)d_in[7];
    const float* Wv = (const float*)d_in[8];
    const float* bv = (const float*)d_in[9];
    float* out = (float*)d_out;

    unsigned short* ws = (unsigned short*)d_ws;
    unsigned short* qh  = ws;                 // 4096*1024 each
    unsigned short* kh  = ws + 4194304;       // K in fragment order
    unsigned short* vT  = ws + 8388608;       // V^T in fragment order
    unsigned short* xqb = ws + 12582912;      // bf16 X inputs
    unsigned short* xkb = ws + 16777216;
    unsigned short* xvb = ws + 20971520;
    unsigned short* wqb = ws + 25165824;      // bf16 W inputs
    unsigned short* wkb = ws + 26214400;
    unsigned short* wvb = ws + 27262976;

    cvt_all<<<dim3(2048, 1, 6), 256, 0, stream>>>(q, k, v, Wq, Wk, Wv,
                                                  xqb, xkb, xvb, wqb, wkb, wvb);

    dim3 pgrid(32, 8, 3);
    proj_gemm_bf16<<<pgrid, 256, 0, stream>>>(xqb, xkb, xvb, wqb, wkb, wvb,
                                              bq, bk, bv, qh, kh, vT);

    attn_kernel<<<dim3(512), 256, 0, stream>>>(qh, kh, vT, mask, out);
}

// Round 18
// 107.684 us; speedup vs baseline: 1.1826x; 1.1551x over previous
//
#include <hip/hip_runtime.h>
#include <hip/hip_bf16.h>
#include <cstdint>

typedef __attribute__((ext_vector_type(8))) short bf16x8;
typedef __attribute__((ext_vector_type(4))) float f32x4;
typedef __attribute__((ext_vector_type(16))) float f32x16;
typedef __attribute__((ext_vector_type(2))) unsigned int u32x2;

static __device__ __forceinline__ unsigned short f2bf(float x) {
    __hip_bfloat16 h = __float2bfloat16(x);
    union { __hip_bfloat16 b; unsigned short u; } c; c.b = h; return c.u;
}
static __device__ __forceinline__ float bf2f(unsigned short b) {
    union { float f; uint32_t u; } v; v.u = ((uint32_t)b) << 16;
    return v.f;
}
static __device__ __forceinline__ float exp2b(float x) {
    return __builtin_amdgcn_exp2f(x);
}
static __device__ __forceinline__ unsigned int cvt_pk_bf16(float lo, float hi) {
    unsigned int r;
    asm("v_cvt_pk_bf16_f32 %0, %1, %2" : "=v"(r) : "v"(lo), "v"(hi));
    return r;
}
static __device__ __forceinline__ void plswap(unsigned int& a, unsigned int& b) {
    u32x2 r = __builtin_amdgcn_permlane32_swap(a, b, false, false);
    a = r[0]; b = r[1];
}
static __device__ __forceinline__ void gload_lds16(const unsigned short* g, unsigned short* l) {
    __builtin_amdgcn_global_load_lds(
        (const __attribute__((address_space(1))) void*)g,
        (__attribute__((address_space(3))) void*)l, 16, 0, 0);
}

// ---------------------------------------------------------------------------
// fp32 -> bf16 convert pass (unchanged).
// ---------------------------------------------------------------------------
__global__ __launch_bounds__(256) void cvt_all(
    const float* __restrict__ xq, const float* __restrict__ xk, const float* __restrict__ xv,
    const float* __restrict__ wq, const float* __restrict__ wk, const float* __restrict__ wv,
    unsigned short* __restrict__ oxq, unsigned short* __restrict__ oxk, unsigned short* __restrict__ oxv,
    unsigned short* __restrict__ owq, unsigned short* __restrict__ owk, unsigned short* __restrict__ owv) {
    const int z = blockIdx.z;
    const float* in = (z == 0) ? xq : (z == 1) ? xk : (z == 2) ? xv
                      : (z == 3) ? wq : (z == 4) ? wk : wv;
    unsigned short* out = (z == 0) ? oxq : (z == 1) ? oxk : (z == 2) ? oxv
                          : (z == 3) ? owq : (z == 4) ? owk : owv;
    const int n8 = (z < 3) ? 524288 : 131072;
    int i = blockIdx.x * 256 + threadIdx.x;
    if (i >= n8) return;
    const float4* ip = (const float4*)in;
    float4 a = ip[2 * i];
    float4 b = ip[2 * i + 1];
    uint4 r;
    r.x = cvt_pk_bf16(a.x, a.y);
    r.y = cvt_pk_bf16(a.z, a.w);
    r.z = cvt_pk_bf16(b.x, b.y);
    r.w = cvt_pk_bf16(b.z, b.w);
    *(uint4*)(out + (size_t)i * 8) = r;
}

// ---------------------------------------------------------------------------
// Projection GEMM, m97 structure. z=0: Q row-major (B,H,S,64).
// z=1: K and z=2: V^T in 32x32x16 MFMA A-FRAGMENT ORDER per head: 32 tiles
// (64 kv each), fragments of 64 lanes x 8 bf16 (A row = lane&31,
// k = (lane>>5)*8 + j), so attention loads each fragment as one coalesced
// 1KB read. K frag (kt,ds): row=kv=32kt+c, k=d=16ds+8hl+j.
// V^T frag (dt,st): row=d=32dt+c, k=kv=16st+8hl+j.
// ---------------------------------------------------------------------------
__global__ __launch_bounds__(256) void proj_gemm_bf16(
    const unsigned short* __restrict__ Xqb, const unsigned short* __restrict__ Xkb,
    const unsigned short* __restrict__ Xvb,
    const unsigned short* __restrict__ Wqb, const unsigned short* __restrict__ Wkb,
    const unsigned short* __restrict__ Wvb,
    const float* __restrict__ bqp, const float* __restrict__ bkp, const float* __restrict__ bvp,
    unsigned short* __restrict__ dq, unsigned short* __restrict__ dk, unsigned short* __restrict__ dv) {
    __shared__ unsigned short a_lds[128 * 64];
    __shared__ unsigned short b_lds[128 * 64];

    const int z = blockIdx.z;
    const unsigned short* X = (z == 0) ? Xqb : (z == 1) ? Xkb : Xvb;
    const unsigned short* W = (z == 0) ? Wqb : (z == 1) ? Wkb : Wvb;
    const float* bias = (z == 0) ? bqp : (z == 1) ? bkp : bvp;
    unsigned short* dst = (z == 0) ? dq : (z == 1) ? dk : dv;

    const int tid = threadIdx.x;
    const int lane = tid & 63;
    const int w = tid >> 6;
    const int lr = lane & 15;
    const int lg = lane >> 4;
    const int m0 = blockIdx.x * 128;
    const int e0 = blockIdx.y * 128;
    const int wrow = (w >> 1) * 64;
    const int wcol = (w & 1) * 64;

    f32x4 acc[4][4] = {};

#pragma unroll 1
    for (int t = 0; t < 16; ++t) {
        const int k0 = t * 64;
        __syncthreads();
#pragma unroll
        for (int i = 0; i < 4; ++i) {
            int c = i * 256 + w * 64 + lane;
            int row = c >> 3;
            int col = (c & 7) * 8;
            gload_lds16(X + (size_t)(m0 + row) * 1024 + k0 + col,
                        a_lds + (size_t)(i * 256 + w * 64) * 8);
            gload_lds16(W + (size_t)(e0 + row) * 1024 + k0 + col,
                        b_lds + (size_t)(i * 256 + w * 64) * 8);
        }
        __syncthreads();

#pragma unroll
        for (int ks = 0; ks < 2; ++ks) {
            const int kk = ks * 32 + lg * 8;
            bf16x8 af[4], bfr[4];
#pragma unroll
            for (int mt = 0; mt < 4; ++mt)
                af[mt] = *(const bf16x8*)(a_lds + (wrow + mt * 16 + lr) * 64 + kk);
#pragma unroll
            for (int nt = 0; nt < 4; ++nt)
                bfr[nt] = *(const bf16x8*)(b_lds + (wcol + nt * 16 + lr) * 64 + kk);
            __builtin_amdgcn_s_setprio(1);
#pragma unroll
            for (int mt = 0; mt < 4; ++mt)
#pragma unroll
                for (int nt = 0; nt < 4; ++nt)
                    acc[mt][nt] = __builtin_amdgcn_mfma_f32_16x16x32_bf16(
                        af[mt], bfr[nt], acc[mt][nt], 0, 0, 0);
            __builtin_amdgcn_s_setprio(0);
        }
    }

    for (int mt = 0; mt < 4; ++mt)
        for (int nt = 0; nt < 4; ++nt)
            for (int i = 0; i < 4; ++i) {
                int m = m0 + wrow + mt * 16 + lg * 4 + i;
                int e = e0 + wcol + nt * 16 + lr;
                float val = acc[mt][nt][i] + bias[e];
                int b = m >> 11, s = m & 2047;
                int h = e >> 6, d = e & 63;
                size_t headoff = (((size_t)b * 16 + h) * 131072);
                if (z == 0) {
                    dst[headoff + (size_t)s * 64 + d] = f2bf(val);
                } else if (z == 1) {
                    int tt = s >> 6;
                    int kt = (s >> 5) & 1;
                    int c  = s & 31;
                    int ds = d >> 4;
                    int hl = (d >> 3) & 1;
                    int j  = d & 7;
                    dst[headoff + tt * 4096 + (kt * 4 + ds) * 512 + (hl * 32 + c) * 8 + j] = f2bf(val);
                } else {
                    int tt = s >> 6;
                    int dt = d >> 5;
                    int c  = d & 31;
                    int st = (s >> 4) & 3;
                    int hl = (s >> 3) & 1;
                    int j  = s & 7;
                    dst[headoff + tt * 4096 + (dt * 4 + st) * 512 + (hl * 32 + c) * 8 + j] = f2bf(val);
                }
            }
}

// ---------------------------------------------------------------------------
// Flash attention v16: 32x32x16 MFMA shape, P fully IN-REGISTER via
// cvt_pk_bf16 + v_permlane32_swap (T12). Per iter: 8 QK^T MFMAs + 8 PV MFMAs
// (half of the 16x16 version's 32), ZERO LDS in the main loop (the P
// round-trip's 12 DS ops are gone), lsum = 1 shfl. Barrier-free; K/V direct
// from L2 in 32x32 A-fragment order; no-max softmax (r12-proven).
// S^T = K.Q^T: lane holds col q = lane&31, rows kv = (r&3)+8*(r>>2)+4*hl
// (+32 per kv-tile). PV B-fragment P^T[kv][q] assembled by pairing
// w[i]=cvt_pk(p[2i],p[2i+1]) and permlane32_swap(w[4st+i], w[4st+2+i]).
// ---------------------------------------------------------------------------
__global__ __launch_bounds__(256) void attn_kernel(
    const unsigned short* __restrict__ Qh,
    const unsigned short* __restrict__ Kf,
    const unsigned short* __restrict__ Vf,
    const unsigned char* __restrict__ mask,
    float* __restrict__ Out) {
    __shared__ float epbuf[4][32 * 68];   // per-wave epilogue transpose [q][d]

    const int tid = threadIdx.x;
    const int lane = tid & 63;
    const int w = tid >> 6;
    const int c = lane & 31;    // q column (QK^T/PV C-layout) / fragment row
    const int hl = lane >> 5;   // lane half

    // T1 XCD swizzle: 512 workgroups, 64 per XCD
    const int bid = blockIdx.x;
    const int wk = (bid & 7) * 64 + (bid >> 3);
    const int x = wk & 15;
    const int bh = wk >> 4;
    const int h = bh & 15;
    const int b = bh >> 4;
    const int q0 = x * 128;

    const size_t headoff = (((size_t)b * 16) + h) * 131072;
    const unsigned short* Qp = Qh + headoff;
    const unsigned char* maskp = mask + b * 2048;

    const unsigned short* kfb = Kf + headoff + (size_t)lane * 8;
    const unsigned short* vfb = Vf + headoff + (size_t)lane * 8;

    // Q as B-operand: col = q = c, k = d = 16*ds + 8*hl + j; scaled.
    const float qscale = 0.125f * 1.44269504088896340736f;
    bf16x8 qf[4];
#pragma unroll
    for (int ds = 0; ds < 4; ++ds) {
        bf16x8 t = *(const bf16x8*)(Qp + (size_t)(q0 + w * 32 + c) * 64 + ds * 16 + hl * 8);
#pragma unroll
        for (int j = 0; j < 8; ++j)
            t[j] = (short)f2bf(bf2f((unsigned short)t[j]) * qscale);
        qf[ds] = t;
    }

    f32x16 o[2] = {};     // O^T: col q=c, row d = 32*dt + (r&3)+8*(r>>2)+4*hl
    float lsum = 0.f;

#pragma unroll 1
    for (int t = 0; t < 32; ++t) {
        const unsigned short* kt_base = kfb + t * 4096;
        const unsigned short* vt_base = vfb + t * 4096;

        // K fragments: 8 coalesced 1KB loads
        bf16x8 kf[2][4];
#pragma unroll
        for (int kt = 0; kt < 2; ++kt)
#pragma unroll
            for (int ds = 0; ds < 4; ++ds)
                kf[kt][ds] = *(const bf16x8*)(kt_base + (kt * 4 + ds) * 512);

        // S^T = K . Q^T  (2 kv-tiles x 4 d-steps)
        f32x16 s[2] = {};
        __builtin_amdgcn_s_setprio(1);
#pragma unroll
        for (int ds = 0; ds < 4; ++ds) {
            s[0] = __builtin_amdgcn_mfma_f32_32x32x16_bf16(kf[0][ds], qf[ds], s[0], 0, 0, 0);
            s[1] = __builtin_amdgcn_mfma_f32_32x32x16_bf16(kf[1][ds], qf[ds], s[1], 0, 0, 0);
        }
        __builtin_amdgcn_s_setprio(0);

        // V fragments: issue now; consumed after softmax
        bf16x8 vf[2][4];
#pragma unroll
        for (int dt = 0; dt < 2; ++dt)
#pragma unroll
            for (int sg = 0; sg < 4; ++sg)
                vf[dt][sg] = *(const bf16x8*)(vt_base + (dt * 4 + sg) * 512);

        unsigned long long mbits = __ballot(maskp[t * 64 + lane] != 0);
        if (mbits) {
#pragma unroll
            for (int kt = 0; kt < 2; ++kt)
#pragma unroll
                for (int r = 0; r < 16; ++r) {
                    int kv = 32 * kt + (r & 3) + 8 * (r >> 2) + 4 * hl;
                    if ((mbits >> kv) & 1ull) s[kt][r] = -1e30f;
                }
        }

        // no-max softmax: p = exp2(s), packed to bf16 pairs in-register
        float ls = 0.f;
        unsigned int wa[8], wb[8];
#pragma unroll
        for (int i = 0; i < 8; ++i) {
            float e0 = exp2b(s[0][2 * i]), e1 = exp2b(s[0][2 * i + 1]);
            ls += e0 + e1;
            wa[i] = cvt_pk_bf16(e0, e1);
            float f0 = exp2b(s[1][2 * i]), f1 = exp2b(s[1][2 * i + 1]);
            ls += f0 + f1;
            wb[i] = cvt_pk_bf16(f0, f1);
        }
        ls += __shfl_xor(ls, 32);
        lsum += ls;

        // P^T B-fragments via permlane32_swap (no LDS)
        bf16x8 pf[2][2];
        {
            unsigned int a0 = wa[0], b0 = wa[2]; plswap(a0, b0);
            unsigned int a1 = wa[1], b1 = wa[3]; plswap(a1, b1);
            union { unsigned int u[4]; bf16x8 v; } pk;
            pk.u[0] = a0; pk.u[1] = a1; pk.u[2] = b0; pk.u[3] = b1; pf[0][0] = pk.v;
            unsigned int a2 = wa[4], b2 = wa[6]; plswap(a2, b2);
            unsigned int a3 = wa[5], b3 = wa[7]; plswap(a3, b3);
            pk.u[0] = a2; pk.u[1] = a3; pk.u[2] = b2; pk.u[3] = b3; pf[0][1] = pk.v;
        }
        {
            unsigned int a0 = wb[0], b0 = wb[2]; plswap(a0, b0);
            unsigned int a1 = wb[1], b1 = wb[3]; plswap(a1, b1);
            union { unsigned int u[4]; bf16x8 v; } pk;
            pk.u[0] = a0; pk.u[1] = a1; pk.u[2] = b0; pk.u[3] = b1; pf[1][0] = pk.v;
            unsigned int a2 = wb[4], b2 = wb[6]; plswap(a2, b2);
            unsigned int a3 = wb[5], b3 = wb[7]; plswap(a3, b3);
            pk.u[0] = a2; pk.u[1] = a3; pk.u[2] = b2; pk.u[3] = b3; pf[1][1] = pk.v;
        }

        // O^T += V^T . P^T  (2 d-tiles x 4 kv-steps)
        __builtin_amdgcn_s_setprio(1);
#pragma unroll
        for (int dt = 0; dt < 2; ++dt)
#pragma unroll
            for (int kt = 0; kt < 2; ++kt)
#pragma unroll
                for (int st = 0; st < 2; ++st)
                    o[dt] = __builtin_amdgcn_mfma_f32_32x32x16_bf16(
                        vf[dt][2 * kt + st], pf[kt][st], o[dt], 0, 0, 0);
        __builtin_amdgcn_s_setprio(0);
    }

    // epilogue (wave-private): transpose O^T -> [q][d] in LDS, coalesced store
    float* ep = epbuf[w];
    float rinv = 1.0f / lsum;
#pragma unroll
    for (int dt = 0; dt < 2; ++dt)
#pragma unroll
        for (int r = 0; r < 16; ++r) {
            int d = 32 * dt + (r & 3) + 8 * (r >> 2) + 4 * hl;
            ep[c * 68 + d] = o[dt][r] * rinv;
        }
#pragma unroll
    for (int j = 0; j < 8; ++j) {
        int id = lane + 64 * j;         // 512 float4 = 32 q x 16
        int row = id >> 4;
        int c4 = (id & 15) << 2;
        float4 val = *(const float4*)(&ep[row * 68 + c4]);
        *(float4*)(&Out[((size_t)b * 2048 + q0 + w * 32 + row) * 1024 + h * 64 + c4]) = val;
    }
}

extern "C" void kernel_launch(void* const* d_in, const int* in_sizes, int n_in,
                              void* d_out, int out_size, void* d_ws, size_t ws_size,
                              hipStream_t stream) {
    const float* v = (const float*)d_in[0];
    const float* k = (const float*)d_in[1];
    const float* q = (const float*)d_in[2];
    const unsigned char* mask = (const unsigned char*)d_in[3];
    const float* Wq = (const float*)d_in[4];
    const float* bq = (const float*)d_in[5];
    const float* Wk = (const float*)d_in[6];
    const float* bk = (const float*)d_in[7];
    const float* Wv = (const float*)d_in[8];
    const float* bv = (const float*)d_in[9];
    float* out = (float*)d_out;

    unsigned short* ws = (unsigned short*)d_ws;
    unsigned short* qh  = ws;                 // 4096*1024 each
    unsigned short* kh  = ws + 4194304;       // K in 32x32 fragment order
    unsigned short* vT  = ws + 8388608;       // V^T in 32x32 fragment order
    unsigned short* xqb = ws + 12582912;      // bf16 X inputs
    unsigned short* xkb = ws + 16777216;
    unsigned short* xvb = ws + 20971520;
    unsigned short* wqb = ws + 25165824;      // bf16 W inputs
    unsigned short* wkb = ws + 26214400;
    unsigned short* wvb = ws + 27262976;

    cvt_all<<<dim3(2048, 1, 6), 256, 0, stream>>>(q, k, v, Wq, Wk, Wv,
                                                  xqb, xkb, xvb, wqb, wkb, wvb);

    dim3 pgrid(32, 8, 3);
    proj_gemm_bf16<<<pgrid, 256, 0, stream>>>(xqb, xkb, xvb, wqb, wkb, wvb,
                                              bq, bk, bv, qh, kh, vT);

    attn_kernel<<<dim3(512), 256, 0, stream>>>(qh, kh, vT, mask, out);
}